// Round 3
// baseline (2787.826 us; speedup 1.0000x reference)
//
#include <hip/hip_runtime.h>
#include <hip/hip_bf16.h>
#include <stdint.h>

#define LN_EPS 1e-5f

typedef __bf16 bf16x8 __attribute__((ext_vector_type(8)));
typedef float f32x4 __attribute__((ext_vector_type(4)));

__device__ __forceinline__ unsigned short f2bf(float x) {
  unsigned u = __float_as_uint(x);
  return (unsigned short)((u + 0x7fffu + ((u >> 16) & 1u)) >> 16);
}

__device__ __forceinline__ void gll16(const void* g, void* l) {
  __builtin_amdgcn_global_load_lds((__attribute__((address_space(1))) void*)g,
                                   (__attribute__((address_space(3))) void*)l, 16, 0, 0);
}

// ---- kernel 1: construct la/lb [8][16][4096] (order-4 tensor product + LN) ----
__global__ __launch_bounds__(256) void k_construct(
    const float* __restrict__ wla, const float* __restrict__ wlb,
    const float* __restrict__ ln1w, const float* __restrict__ ln1b,
    const float* __restrict__ ln2w, const float* __restrict__ ln2b,
    float* __restrict__ la, float* __restrict__ lb) {
  const int s = blockIdx.x;
  const int t = threadIdx.x;
  __shared__ float w01[1024];
  __shared__ float w23[1024];
  __shared__ float red[8];
  for (int g = 0; g < 2; ++g) {
    const float* wl = g ? wlb : wla;
    for (int half = 0; half < 2; ++half) {
      const float* lnw  = half ? ln2w : ln1w;
      const float* lnbv = half ? ln2b : ln1b;
      const float* w0 = wl + (2*half + 0)*1024 + s*128;
      const float* w1 = wl + (2*half + 1)*1024 + s*128;
      float* buf = half ? w23 : w01;
      float v[4];
      float sum = 0.f, sumsq = 0.f;
      #pragma unroll
      for (int q = 0; q < 4; ++q) {
        int idx = t + 256*q;
        int r = idx >> 6, m = idx & 63;
        float val = w0[r*8 + (m >> 3)] * w1[r*8 + (m & 7)];
        v[q] = val; sum += val; sumsq += val*val;
      }
      #pragma unroll
      for (int off = 32; off; off >>= 1) {
        sum   += __shfl_down(sum, off);
        sumsq += __shfl_down(sumsq, off);
      }
      if ((t & 63) == 0) { red[t >> 6] = sum; red[4 + (t >> 6)] = sumsq; }
      __syncthreads();
      float fs  = red[0] + red[1] + red[2] + red[3];
      float fss = red[4] + red[5] + red[6] + red[7];
      float mu  = fs * (1.f/1024.f);
      float var = fss * (1.f/1024.f) - mu*mu;
      float rs  = rsqrtf(var + LN_EPS);
      __syncthreads();
      #pragma unroll
      for (int q = 0; q < 4; ++q) {
        int idx = t + 256*q;
        buf[idx] = (v[q] - mu) * rs * lnw[idx] + lnbv[idx];
      }
      __syncthreads();
    }
    float* dst = (g ? lb : la) + s*65536;
    for (int q = 0; q < 256; ++q) {
      int f = t + 256*q;
      int rb = (f >> 12) << 6;
      dst[f] = w01[rb + ((f >> 6) & 63)] * w23[rb + (f & 63)];
    }
    __syncthreads();
  }
}

// ---- kernel 2: mixture. A[b][r][d] f32; Bmb[(b*4096+o)*64 + r] bf16 (zero-padded 16..63) ----
__global__ __launch_bounds__(256) void k_mix(
    const float* __restrict__ la, const float* __restrict__ lb,
    const float* __restrict__ module_logits, const int* __restrict__ task_ids,
    float* __restrict__ A, unsigned short* __restrict__ Bmb) {
  int gid = blockIdx.x*256 + threadIdx.x;   // 0..32767
  int b = gid >> 12, d = gid & 4095;
  int task = task_ids[b];
  float mwv[8]; float ssum = 0.f;
  #pragma unroll
  for (int s = 0; s < 8; ++s) {
    float p = 1.f / (1.f + expf(-module_logits[task*8 + s]));
    mwv[s] = p; ssum += p;
  }
  float inv = 1.f / (ssum + 1e-12f);
  unsigned pk[8];
  #pragma unroll
  for (int r = 0; r < 16; ++r) {
    float av = 0.f, bv = 0.f;
    #pragma unroll
    for (int s = 0; s < 8; ++s) {
      float w = mwv[s] * inv;
      av += w * la[(s*16 + r)*4096 + d];
      bv += w * lb[(s*16 + r)*4096 + d];
    }
    A[(b*16 + r)*4096 + d] = av;
    unsigned hv = f2bf(bv);
    if (r & 1) pk[r >> 1] |= hv << 16; else pk[r >> 1] = hv;
  }
  uint4* dst = (uint4*)(Bmb + (size_t)gid*64);
  uint4 a0; a0.x = pk[0]; a0.y = pk[1]; a0.z = pk[2]; a0.w = pk[3];
  uint4 a1; a1.x = pk[4]; a1.y = pk[5]; a1.z = pk[6]; a1.w = pk[7];
  uint4 z;  z.x = 0; z.y = 0; z.z = 0; z.w = 0;
  dst[0] = a0; dst[1] = a1;
  dst[2] = z; dst[3] = z; dst[4] = z; dst[5] = z; dst[6] = z; dst[7] = z;
}

// ---- kernel 3: cast W -> bf16 ----
__global__ __launch_bounds__(256) void k_castw(const float* __restrict__ w,
                                               unsigned short* __restrict__ wb) {
  int i = blockIdx.x*256 + threadIdx.x;
  float4 v = ((const float4*)w)[i];
  uint2 o;
  o.x = (unsigned)f2bf(v.x) | ((unsigned)f2bf(v.y) << 16);
  o.y = (unsigned)f2bf(v.z) | ((unsigned)f2bf(v.w) << 16);
  ((uint2*)wb)[i] = o;
}

// ---- kernel 4: 32 rows/block: xb = bf16(x); hb[row][0..63] = bf16(h/16), zero-padded ----
__global__ __launch_bounds__(256) void k_rowh(
    const float* __restrict__ x, const float* __restrict__ A,
    unsigned short* __restrict__ xb, unsigned short* __restrict__ hb) {
  const int tid = threadIdx.x;
  const int rl = tid >> 3, seg = tid & 7;
  const int row = blockIdx.x * 32 + rl;
  const int b = (blockIdx.x * 32) >> 11;        // 32-row block never crosses batch
  const float* xrow = x + (size_t)row * 4096;
  const float* Ab = A + b * 65536;
  unsigned short* xbrow = xb + (size_t)row * 4096;
  float p[16];
  #pragma unroll
  for (int r = 0; r < 16; ++r) p[r] = 0.f;
  for (int i = 0; i < 128; ++i) {
    int d0 = (i * 8 + seg) * 4;
    float4 xv = *(const float4*)(xrow + d0);
    ushort4 o; o.x = f2bf(xv.x); o.y = f2bf(xv.y); o.z = f2bf(xv.z); o.w = f2bf(xv.w);
    *(ushort4*)(xbrow + d0) = o;
    #pragma unroll
    for (int r = 0; r < 16; ++r) {
      float4 av = *(const float4*)(Ab + r * 4096 + d0);
      p[r] += xv.x * av.x + xv.y * av.y + xv.z * av.z + xv.w * av.w;
    }
  }
  #pragma unroll
  for (int r = 0; r < 16; ++r) {
    p[r] += __shfl_down(p[r], 4, 8);
    p[r] += __shfl_down(p[r], 2, 8);
    p[r] += __shfl_down(p[r], 1, 8);
  }
  unsigned short* hrow = hb + (size_t)row * 64;
  if (seg == 0) {
    unsigned pk[8];
    #pragma unroll
    for (int r = 0; r < 16; ++r) {
      unsigned hv = f2bf(p[r] * 0.0625f);
      if (r & 1) pk[r >> 1] |= hv << 16; else pk[r >> 1] = hv;
    }
    uint4 v0; v0.x = pk[0]; v0.y = pk[1]; v0.z = pk[2]; v0.w = pk[3];
    uint4 v1; v1.x = pk[4]; v1.y = pk[5]; v1.z = pk[6]; v1.w = pk[7];
    ((uint4*)hrow)[0] = v0; ((uint4*)hrow)[1] = v1;
  } else if (seg < 4) {
    uint4 z; z.x = z.y = z.z = z.w = 0;
    ((uint4*)hrow)[seg * 2] = z; ((uint4*)hrow)[seg * 2 + 1] = z;
  }
}

// ---- kernel 5: 256x256 8-phase GEMM: C = Xb·Wbᵀ + bias + adapter tile (hb·Bmbᵀ) ----
// LDS: 2 buffers x 4 regions {B0,B1,A0,A1} x 16KB. st_16x32 swizzle both sides.
#define DS_A(BOFF, m, ks) (*(const bf16x8*)(ldsc + (BOFF) + abase[m] + (ks) * 64))
#define DS_B(BOFF, n, ks) (*(const bf16x8*)(ldsc + (BOFF) + bbase[n] + (ks) * 64))

#define VM6 asm volatile("s_waitcnt vmcnt(6)" ::: "memory");
#define VM0 asm volatile("s_waitcnt vmcnt(0)" ::: "memory");

#define TILE(BOFF, VMSTMT) { \
  bf16x8 b0f[4], b1f[4], a0f[4], a1f[4], a2f[4], a3f[4]; \
  /* phase 0: read all B (both ks) + A m0-3 ks0; issue (t+1).A1 */ \
  _Pragma("unroll") for (int n = 0; n < 4; ++n) { b0f[n] = DS_B(BOFF,n,0); b1f[n] = DS_B(BOFF,n,1); } \
  _Pragma("unroll") for (int m = 0; m < 4; ++m) a0f[m] = DS_A(BOFF,m,0); \
  issue(); \
  __builtin_amdgcn_sched_barrier(0); \
  __builtin_amdgcn_s_barrier(); \
  asm volatile("s_waitcnt lgkmcnt(0)" ::: "memory"); \
  __builtin_amdgcn_sched_barrier(0); \
  __builtin_amdgcn_s_setprio(1); \
  _Pragma("unroll") for (int m = 0; m < 4; ++m) \
    _Pragma("unroll") for (int n = 0; n < 4; ++n) \
      acc[m][n] = __builtin_amdgcn_mfma_f32_16x16x32_bf16(a0f[m], b0f[n], acc[m][n], 0, 0, 0); \
  __builtin_amdgcn_s_setprio(0); \
  __builtin_amdgcn_sched_barrier(0); \
  __builtin_amdgcn_s_barrier(); \
  /* phase 1: read A m0-3 ks1 + A m4-7 ks0; issue (t+2).B0 */ \
  _Pragma("unroll") for (int m = 0; m < 4; ++m) a1f[m] = DS_A(BOFF,m,1); \
  _Pragma("unroll") for (int m = 0; m < 4; ++m) a2f[m] = DS_A(BOFF,4+m,0); \
  issue(); \
  __builtin_amdgcn_sched_barrier(0); \
  __builtin_amdgcn_s_barrier(); \
  asm volatile("s_waitcnt lgkmcnt(0)" ::: "memory"); \
  __builtin_amdgcn_sched_barrier(0); \
  __builtin_amdgcn_s_setprio(1); \
  _Pragma("unroll") for (int m = 0; m < 4; ++m) \
    _Pragma("unroll") for (int n = 0; n < 4; ++n) \
      acc[m][n] = __builtin_amdgcn_mfma_f32_16x16x32_bf16(a1f[m], b1f[n], acc[m][n], 0, 0, 0); \
  __builtin_amdgcn_s_setprio(0); \
  __builtin_amdgcn_sched_barrier(0); \
  __builtin_amdgcn_s_barrier(); \
  /* phase 2: read A m4-7 ks1; issue (t+2).B1 */ \
  _Pragma("unroll") for (int m = 0; m < 4; ++m) a3f[m] = DS_A(BOFF,4+m,1); \
  issue(); \
  __builtin_amdgcn_sched_barrier(0); \
  __builtin_amdgcn_s_barrier(); \
  asm volatile("s_waitcnt lgkmcnt(0)" ::: "memory"); \
  __builtin_amdgcn_sched_barrier(0); \
  __builtin_amdgcn_s_setprio(1); \
  _Pragma("unroll") for (int m = 0; m < 4; ++m) \
    _Pragma("unroll") for (int n = 0; n < 4; ++n) \
      acc[4+m][n] = __builtin_amdgcn_mfma_f32_16x16x32_bf16(a2f[m], b0f[n], acc[4+m][n], 0, 0, 0); \
  __builtin_amdgcn_s_setprio(0); \
  __builtin_amdgcn_sched_barrier(0); \
  __builtin_amdgcn_s_barrier(); \
  /* phase 3: no reads; issue (t+2).A0; vmcnt gate for next tile */ \
  issue(); \
  __builtin_amdgcn_sched_barrier(0); \
  VMSTMT \
  __builtin_amdgcn_s_barrier(); \
  __builtin_amdgcn_s_setprio(1); \
  _Pragma("unroll") for (int m = 0; m < 4; ++m) \
    _Pragma("unroll") for (int n = 0; n < 4; ++n) \
      acc[4+m][n] = __builtin_amdgcn_mfma_f32_16x16x32_bf16(a3f[m], b1f[n], acc[4+m][n], 0, 0, 0); \
  __builtin_amdgcn_s_setprio(0); \
  __builtin_amdgcn_sched_barrier(0); \
  __builtin_amdgcn_s_barrier(); \
}

__global__ __launch_bounds__(512, 2) void k_gemm256(
    const unsigned short* __restrict__ xb, const unsigned short* __restrict__ wb,
    const unsigned short* __restrict__ hb, const unsigned short* __restrict__ Bmb,
    const float* __restrict__ bias, float* __restrict__ out) {
  __shared__ int4 smem[8192];            // 128 KiB
  char* ldsc = (char*)smem;
  const int tid = threadIdx.x;
  const int bid = blockIdx.x;
  const int swz = ((bid & 7) << 7) + (bid >> 3);   // 1024 blocks, 8 XCDs
  const int mt = swz >> 4, nt = swz & 15;
  const int row0 = mt << 8, col0 = nt << 8;
  const int b = row0 >> 11;                        // 256-row tile within one batch
  const int wid = tid >> 6, lane = tid & 63;
  const int wr = wid >> 2, wc = wid & 3;           // wave grid 2M x 4N
  const int u = lane >> 4, lr = lane & 15;

  // ds_read lane bases (region-relative, st_16x32 swizzled; ks adds +64B)
  int abase[8], bbase[4];
  #pragma unroll
  for (int m = 0; m < 8; ++m) {
    int rowin = m * 16 + lr;
    abase[m] = (2 + wr) * 16384 + rowin * 128 + ((u << 4) ^ ((rowin & 4) << 3));
  }
  #pragma unroll
  for (int n = 0; n < 4; ++n) {
    int rowin = (wc & 1) * 64 + n * 16 + lr;
    bbase[n] = (wc >> 1) * 16384 + rowin * 128 + ((u << 4) ^ ((rowin & 4) << 3));
  }

  // staging sources: linear LDS dest q <- global element at q ^ s(q)
  int q0 = tid * 16, q1 = 8192 + tid * 16;
  int qs0 = q0 ^ (((q0 >> 9) & 1) << 5), qs1 = q1 ^ (((q1 >> 9) & 1) << 5);
  int rowq0 = qs0 >> 7, colb0 = qs0 & 127;
  int rowq1 = qs1 >> 7, colb1 = qs1 & 127;
  const char* xc  = (const char*)xb;
  const char* wcb = (const char*)wb;
  const char* srcB0 = wcb + (size_t)(col0 + rowq0) * 8192 + colb0;
  const char* srcB1 = wcb + (size_t)(col0 + rowq1) * 8192 + colb1;
  const char* srcA0 = xc  + (size_t)(row0 + rowq0) * 8192 + colb0;
  const char* srcA1 = xc  + (size_t)(row0 + rowq1) * 8192 + colb1;
  const char* adB0 = (const char*)Bmb + (size_t)b * 524288 + (size_t)(col0 + rowq0) * 128 + colb0;
  const char* adB1 = (const char*)Bmb + (size_t)b * 524288 + (size_t)(col0 + rowq1) * 128 + colb1;
  const char* adA0 = (const char*)hb  + (size_t)(row0 + rowq0) * 128 + colb0;
  const char* adA1 = (const char*)hb  + (size_t)(row0 + rowq1) * 128 + colb1;

  // half-tile issue stream: h = 4*tau + part, part in {B0,B1,A0,A1}; tiles 0..64
  int H = 0;
  auto issue = [&]() {
    int h = H++;
    if (h > 259) return;                           // 65 tiles x 4 halves
    int tau = h >> 2, part = h & 3;
    char* d = ldsc + ((tau & 1) << 16) + part * 16384 + tid * 16;
    if (tau < 64) {
      size_t ko = (size_t)tau * 128 + ((part & 1) ? 1048576u : 0u);
      const char* s0 = ((part & 2) ? srcA0 : srcB0) + ko;
      const char* s1 = ((part & 2) ? srcA1 : srcB1) + ko;
      gll16(s0, d); gll16(s1, d + 8192);
    } else {                                       // adapter tile (hb / Bmb)
      size_t hi = (part & 1) ? 16384u : 0u;
      const char* s0 = ((part & 2) ? adA0 : adB0) + hi;
      const char* s1 = ((part & 2) ? adA1 : adB1) + hi;
      gll16(s0, d); gll16(s1, d + 8192);
    }
  };

  f32x4 acc[8][4];
  #pragma unroll
  for (int i = 0; i < 8; ++i)
    #pragma unroll
    for (int j = 0; j < 4; ++j) acc[i][j] = (f32x4){0.f, 0.f, 0.f, 0.f};

  // prologue: tile0 fully + tile1 {B0,B1,A0}; wait tile0 landed (3 halves in flight)
  for (int i = 0; i < 7; ++i) issue();
  __builtin_amdgcn_sched_barrier(0);
  VM6
  __builtin_amdgcn_s_barrier();

  for (int tt = 0; tt < 31; ++tt) {
    TILE(0, VM6)        // even tile
    TILE(65536, VM6)    // odd tile
  }
  TILE(0, VM6)          // tile 62
  TILE(65536, VM0)      // tile 63 (tail: drain so adapter data is resident)
  TILE(0, )             // tile 64 = adapter (no more issues, no wait)

  // epilogue
  float bv[4];
  #pragma unroll
  for (int n = 0; n < 4; ++n) bv[n] = bias[col0 + wc * 64 + n * 16 + lr];
  #pragma unroll
  for (int m = 0; m < 8; ++m) {
    int rb = row0 + wr * 128 + m * 16 + u * 4;
    #pragma unroll
    for (int n = 0; n < 4; ++n) {
      int cl = col0 + wc * 64 + n * 16 + lr;
      #pragma unroll
      for (int q = 0; q < 4; ++q)
        out[(size_t)(rb + q) * 4096 + cl] = acc[m][n][q] + bv[n];
    }
  }
}

extern "C" void kernel_launch(void* const* d_in, const int* in_sizes, int n_in,
                              void* d_out, int out_size, void* d_ws, size_t ws_size,
                              hipStream_t stream) {
  const float* x             = (const float*)d_in[0];
  const int*   task_ids      = (const int*)d_in[1];
  const float* weight        = (const float*)d_in[2];
  const float* bias          = (const float*)d_in[3];
  const float* module_logits = (const float*)d_in[4];
  const float* wla           = (const float*)d_in[5];
  const float* wlb           = (const float*)d_in[6];
  const float* ln1w          = (const float*)d_in[7];
  const float* ln1b          = (const float*)d_in[8];
  const float* ln2w          = (const float*)d_in[9];
  const float* ln2b          = (const float*)d_in[10];
  float* out = (float*)d_out;

  char* ws = (char*)d_ws;
  unsigned short* xb  = (unsigned short*)(ws);                       // 128 MiB
  unsigned short* wb  = (unsigned short*)(ws + 134217728);           // 32 MiB
  float* la           = (float*)(ws + 167772160);                    // 2 MiB
  float* lb           = (float*)(ws + 169869312);                    // 2 MiB
  float* A            = (float*)(ws + 171966464);                    // 2 MiB
  unsigned short* Bmb = (unsigned short*)(ws + 174063616);           // 4 MiB
  unsigned short* hb  = (unsigned short*)(ws + 178257920);           // 2 MiB

  k_construct<<<8, 256, 0, stream>>>(wla, wlb, ln1w, ln1b, ln2w, ln2b, la, lb);
  k_mix<<<128, 256, 0, stream>>>(la, lb, module_logits, task_ids, A, Bmb);
  k_castw<<<16384, 256, 0, stream>>>(weight, wb);
  k_rowh<<<512, 256, 0, stream>>>(x, A, xb, hb);
  k_gemm256<<<1024, 512, 0, stream>>>(xb, wb, hb, Bmb, bias, out);
}